// Round 6
// baseline (2665.902 us; speedup 1.0000x reference)
//
#include <hip/hip_runtime.h>
#include <cstdint>
#include <cstddef>

typedef unsigned int  uint_t;
typedef unsigned short ushort_t;

// ---- shapes (fixed for this problem) ----
constexpr int B_  = 64;
constexpr int S_  = 128;
constexpr int D_  = 100;   // triple embedding dim
constexpr int E_  = 300;   // word embedding dim
constexpr int H_  = 256;   // hidden
constexpr int KIN = 512;   // LSTM input 500 padded to 512 for MFMA K
constexpr int NG  = 1024;  // 4*H gates
constexpr int M_  = B_ * S_;  // 8192

// ---- workspace layout (bytes) ----
constexpr size_t OFF_WT   = 0;                                  // W_ent^T bf16 [200][100]  (40000 B)
constexpr size_t OFF_FLAG = 40000;                              // int: 1 if inputs are fp32, 0 if bf16
constexpr size_t OFF_WIH  = 40960;                              // W_ih padded bf16 [1024][512]
constexpr size_t OFF_WHH  = OFF_WIH + (size_t)NG * KIN * 2;     // W4: W_hh f16x2, row-major [1024][128] u32
constexpr size_t OFF_TIN  = OFF_WHH + (size_t)128 * NG * 4;     // t_in bf16 [8192][512]
constexpr size_t OFF_XG   = OFF_TIN + (size_t)M_ * KIN * 2;     // xg f32 [8192][1024]
constexpr size_t OFF_HOUT = OFF_XG + (size_t)M_ * NG * 4;       // h f32 [8192][256]
// total ~50 MB

// ---- helpers ----
__device__ __forceinline__ float b2f(ushort_t u) {
  union { uint_t u; float f; } v; v.u = ((uint_t)u) << 16; return v.f;
}
__device__ __forceinline__ float blo(uint_t u) {
  union { uint_t u; float f; } v; v.u = u << 16; return v.f;
}
__device__ __forceinline__ float bhi(uint_t u) {
  union { uint_t u; float f; } v; v.u = u & 0xffff0000u; return v.f;
}
__device__ __forceinline__ ushort_t f2b(float f) {  // RNE float->bf16
  union { float f; uint_t u; } v; v.f = f;
  uint_t r = (v.u + 0x7fffu + ((v.u >> 16) & 1u)) >> 16;
  return (ushort_t)r;
}
__device__ __forceinline__ ushort_t f16bits(float f) {
  _Float16 h = (_Float16)f;
  union { _Float16 h; ushort_t u; } v; v.h = h; return v.u;
}
__device__ __forceinline__ float fast_tanh(float x) {
  float e = __expf(2.f * x);
  return 1.f - 2.f / (e + 1.f);
}
__device__ __forceinline__ float sigm(float x) {
  return 1.f / (1.f + __expf(-x));
}
// dtype-flexible load of an external "float" tensor
__device__ __forceinline__ float ldv(const void* p, size_t i, int f32) {
  return f32 ? ((const float*)p)[i] : b2f(((const ushort_t*)p)[i]);
}

#if defined(__has_builtin)
#if __has_builtin(__builtin_amdgcn_fdot2)
#define HAVE_FDOT2 1
#endif
#endif

typedef _Float16 half2v __attribute__((ext_vector_type(2)));

__device__ __forceinline__ float dot2(uint_t w, uint_t h, float acc) {
#ifdef HAVE_FDOT2
  union { uint_t u; half2v v; } a, b; a.u = w; b.u = h;
  return __builtin_amdgcn_fdot2(a.v, b.v, acc, false);
#else
  union { uint_t u; _Float16 h[2]; } a, b; a.u = w; b.u = h;
  acc += (float)a.h[0] * (float)b.h[0];
  acc += (float)a.h[1] * (float)b.h[1];
  return acc;
#endif
}

// =====================================================================
// K_detect: decide whether external float tensors are fp32 or bf16.
// =====================================================================
__global__ __launch_bounds__(64) void k_detect(const uint_t* __restrict__ emb_w,
                                               char* __restrict__ ws)
{
  int tid = threadIdx.x;
  int hits = 0;
  for (int i = 0; i < 8; ++i) {
    uint_t w = emb_w[i * 64 + tid];
    uint_t e = (w >> 7) & 0xffu;   // exponent field of lo-ushort-as-bf16
    hits += (e >= 140) ? 1 : 0;
  }
  for (int off = 32; off > 0; off >>= 1) hits += __shfl_down(hits, off);
  if (tid == 0) *(int*)(ws + OFF_FLAG) = (hits >= 32) ? 1 : 0;
}

// =====================================================================
// K0: weight prep. Wt = W_ent^T (bf16); W_ih padded K 500->512 (bf16);
// W_hh -> W4: f16x2 packed, ROW-MAJOR [row][128] u32 (for streaming).
// =====================================================================
__global__ __launch_bounds__(256) void k0_prep(
    const void* __restrict__ W_ent, const void* __restrict__ W_ih,
    const void* __restrict__ W_hh, char* __restrict__ ws)
{
  const int f32 = *(const int*)(ws + OFF_FLAG);
  int id = blockIdx.x * 256 + threadIdx.x;
  ushort_t* Wt  = (ushort_t*)(ws + OFF_WT);
  ushort_t* Wp  = (ushort_t*)(ws + OFF_WIH);
  uint_t*   W4u = (uint_t*)(ws + OFF_WHH);
  if (id < 20000) {
    int k = id / 100, d = id % 100;
    Wt[id] = f2b(ldv(W_ent, (size_t)d * 200 + k, f32));   // Wt[k][d] = W_ent[d][k]
  } else if (id < 20000 + NG * KIN) {
    int i = id - 20000;
    int n = i >> 9, k = i & 511;
    Wp[i] = (k < 500) ? f2b(ldv(W_ih, (size_t)n * 500 + k, f32)) : (ushort_t)0;
  } else if (id < 20000 + NG * KIN + 128 * NG) {
    int i = id - 20000 - NG * KIN;
    int row = i >> 7, kk = i & 127;
    ushort_t lo = f16bits(ldv(W_hh, (size_t)row * 256 + 2 * kk,     f32));
    ushort_t hi = f16bits(ldv(W_hh, (size_t)row * 256 + 2 * kk + 1, f32));
    W4u[i] = (uint_t)lo | ((uint_t)hi << 16);   // W4u[row*128 + kk]
  }
}

// =====================================================================
// K1: triple graph attention; 8 tokens per block (amortize 40 KB W^T
// staging). 1024 blocks x 256 threads. Writes t_in bf16 [m][512].
// =====================================================================
__global__ __launch_bounds__(256) void k1_graph(
    const int* __restrict__ inputs, const int* __restrict__ triples,
    const int* __restrict__ id2, const void* __restrict__ emb,
    const void* __restrict__ ent, const void* __restrict__ rel,
    char* __restrict__ ws)
{
  __shared__ __align__(16) ushort_t Wl[20000];   // W^T [k][d], 40000 B
  __shared__ float ht_l[10][200];
  __shared__ float er_l[10][100];
  __shared__ float e_l[10];
  __shared__ float alpha_l[10];
  __shared__ int   trip_l[30];
  __shared__ int   vflag;

  const int tid = threadIdx.x;
  const int m0  = blockIdx.x * 8;
  const int f32 = *(const int*)(ws + OFF_FLAG);
  const ushort_t* Wt = (const ushort_t*)(ws + OFF_WT);
  ushort_t* tin = (ushort_t*)(ws + OFF_TIN);

  // stage W^T once per block (coalesced 16B copies)
  {
    const uint4* src = (const uint4*)Wt;
    uint4* dst = (uint4*)Wl;
    for (int i = tid; i < 2500; i += 256) dst[i] = src[i];
  }

  for (int j = 0; j < 8; ++j) {
    const int m = m0 + j;
    __syncthreads();   // previous token's reads done before overwrite
    if (tid < 30) trip_l[tid] = triples[(size_t)m * 30 + tid];
    if (tid == 0) vflag = 0;
    if (tid < 10) e_l[tid] = 0.f;
    __syncthreads();
    if (tid < 10 && id2[(size_t)m * 10 + tid] != -1) atomicOr(&vflag, 1);

    for (int i = tid; i < 2000; i += 256) {
      int t = i / 200, k = i % 200;
      int row = trip_l[t * 3 + (k < 100 ? 0 : 1)];
      int kk = (k < 100) ? k : k - 100;
      ht_l[t][k] = ldv(ent, (size_t)row * 100 + kk, f32);
    }
    for (int i = tid; i < 1000; i += 256) {
      int t = i / 100, d = i % 100;
      er_l[t][d] = ldv(rel, (size_t)trip_l[t * 3 + 2] * 100 + d, f32);
    }
    {
      int w = inputs[m];
      for (int cc = tid; cc < 300; cc += 256)
        tin[(size_t)m * KIN + cc] = f2b(ldv(emb, (size_t)w * E_ + cc, f32));
      if (tid < 12) tin[(size_t)m * KIN + 500 + tid] = 0;
    }
    __syncthreads();

    // 1000 dots (t,d) of length 200; thread: 1 t x 4 d
    if (tid < 250) {
      int t = tid / 25, d4 = tid % 25;
      float a0 = 0, a1 = 0, a2 = 0, a3 = 0;
      for (int k = 0; k < 200; ++k) {
        uint2 wu = *(const uint2*)&Wl[k * 100 + 4 * d4];
        float h0 = ht_l[t][k];
        a0 += blo(wu.x) * h0; a1 += bhi(wu.x) * h0;
        a2 += blo(wu.y) * h0; a3 += bhi(wu.y) * h0;
      }
      int d = 4 * d4;
      float s = fast_tanh(a0) * er_l[t][d]     + fast_tanh(a1) * er_l[t][d + 1]
              + fast_tanh(a2) * er_l[t][d + 2] + fast_tanh(a3) * er_l[t][d + 3];
      atomicAdd(&e_l[t], s);
    }
    __syncthreads();
    if (tid == 0) {  // softmax over 10 triples
      float mx = e_l[0];
      for (int t = 1; t < 10; ++t) mx = fmaxf(mx, e_l[t]);
      float s = 0.f;
      for (int t = 0; t < 10; ++t) { float v = __expf(e_l[t] - mx); alpha_l[t] = v; s += v; }
      float inv = 1.f / s;
      for (int t = 0; t < 10; ++t) alpha_l[t] *= inv;
    }
    __syncthreads();
    if (tid < 200) {
      float g = 0.f;
#pragma unroll
      for (int t = 0; t < 10; ++t) g += alpha_l[t] * ht_l[t][tid];
      if (!vflag) g = 0.f;
      tin[(size_t)m * KIN + 300 + tid] = f2b(g);
    }
  }
}

// =====================================================================
// K2: xg = t_in @ W_ih^T + b.  MFMA 16x16x32 bf16, 128x128 tiles, BK=32.
// =====================================================================
typedef __attribute__((ext_vector_type(8))) short short8;
typedef __attribute__((ext_vector_type(4))) float f32x4;

__global__ __launch_bounds__(256) void k2_xg(
    const void* __restrict__ bl, char* __restrict__ ws)
{
  __shared__ __align__(16) ushort_t As[128 * 32];
  __shared__ __align__(16) ushort_t Bs[128 * 32];
  const ushort_t* A  = (const ushort_t*)(ws + OFF_TIN);
  const ushort_t* Bw = (const ushort_t*)(ws + OFF_WIH);
  float* xg = (float*)(ws + OFF_XG);
  const int f32 = *(const int*)(ws + OFF_FLAG);

  const int tid = threadIdx.x;
  const int m0 = blockIdx.x * 128;
  const int n0 = blockIdx.y * 128;
  const int lane = tid & 63, wv = tid >> 6;
  const int wm = wv & 1, wn = wv >> 1;
  const int g = lane >> 4, r = lane & 15;

  f32x4 acc[4][4] = {};

  for (int ks = 0; ks < 16; ++ks) {
    const int k0 = ks * 32;
    {
      int c0 = tid, c1 = tid + 256;
      uint4 a0 = *(const uint4*)(A  + (size_t)(m0 + (c0 >> 2)) * KIN + k0 + ((c0 & 3) << 3));
      uint4 a1 = *(const uint4*)(A  + (size_t)(m0 + (c1 >> 2)) * KIN + k0 + ((c1 & 3) << 3));
      uint4 b0 = *(const uint4*)(Bw + (size_t)(n0 + (c0 >> 2)) * KIN + k0 + ((c0 & 3) << 3));
      uint4 b1 = *(const uint4*)(Bw + (size_t)(n0 + (c1 >> 2)) * KIN + k0 + ((c1 & 3) << 3));
      ((uint4*)As)[c0] = a0; ((uint4*)As)[c1] = a1;
      ((uint4*)Bs)[c0] = b0; ((uint4*)Bs)[c1] = b1;
    }
    __syncthreads();
    short8 av[4], bv[4];
#pragma unroll
    for (int i = 0; i < 4; ++i)
      av[i] = *(const short8*)&As[(wm * 64 + i * 16 + r) * 32 + g * 8];
#pragma unroll
    for (int j = 0; j < 4; ++j)
      bv[j] = *(const short8*)&Bs[(wn * 64 + j * 16 + r) * 32 + g * 8];
#pragma unroll
    for (int i = 0; i < 4; ++i)
#pragma unroll
      for (int j = 0; j < 4; ++j)
        acc[i][j] = __builtin_amdgcn_mfma_f32_16x16x32_bf16(av[i], bv[j], acc[i][j], 0, 0, 0);
    __syncthreads();
  }
#pragma unroll
  for (int j = 0; j < 4; ++j) {
    int n = n0 + wn * 64 + j * 16 + r;
    float bias = ldv(bl, n, f32);
#pragma unroll
    for (int i = 0; i < 4; ++i) {
      int mrow = m0 + wm * 64 + i * 16 + g * 4;
#pragma unroll
      for (int rr = 0; rr < 4; ++rr)
        xg[(size_t)(mrow + rr) * NG + n] = acc[i][j][rr] + bias;
    }
  }
}

// =====================================================================
// K3: recurrent LSTM, L2-STREAMING weights (no register residency, no
// LDS weights — allocator-proof). 64 blocks x 1024 threads. Quad of
// lanes owns hidden unit u=tid>>2 (4 gate rows); thread owns K-quarter
// (32 f16x2 words = 8 uint4 per row). Every step each thread streams
// its 32 uint4 weight slice from L2 (W4 is 512 KB, resident per XCD;
// per-block share ~575 GB/s > LDS b128 rate). Rotated j4=(r+t)&7 keeps
// addresses loop-variant so LICM can't hoist-and-spill. h in a 1 KB
// LDS double-buffer; one barrier/step; quad-combine via shfl_xor.
// Fused attention pooling + logits epilogue.
// =====================================================================
__global__ __launch_bounds__(1024) void k3_lstm(
    const int* __restrict__ lengths, const void* __restrict__ attn_w,
    const void* __restrict__ attn_b, const void* __restrict__ out_w,
    const void* __restrict__ out_b, char* __restrict__ ws,
    void* __restrict__ out)
{
  __shared__ __align__(16) ushort_t hbuf[512];   // [2][256] f16
  __shared__ float aw[256];
  __shared__ float sc[128];
  __shared__ float at[256];
  __shared__ float red[256];

  const int tid = threadIdx.x;
  const int b   = blockIdx.x;
  const int u   = tid >> 2;        // hidden unit 0..255
  const int q   = tid & 3;         // K-quarter
  const int q8  = q * 8;           // first uint4 index of my K-slice

  const uint4* W44 = (const uint4*)(ws + OFF_WHH);   // [row][32] uint4
  const float* xg = (const float*)(ws + OFF_XG);
  float* hout = (float*)(ws + OFF_HOUT);

  const uint4* wr0 = W44 + (size_t)(u      ) * 32 + q8;
  const uint4* wr1 = W44 + (size_t)(u + 256) * 32 + q8;
  const uint4* wr2 = W44 + (size_t)(u + 512) * 32 + q8;
  const uint4* wr3 = W44 + (size_t)(u + 768) * 32 + q8;

  if (tid < 512) hbuf[tid] = 0;
  float c = 0.f;
  __syncthreads();

  const int bm = b * S_;
  for (int t = 0; t < S_; ++t) {
    const int cur = t & 1;
    const float* xp = xg + (size_t)(bm + t) * NG;
    float x0 = xp[u], x1 = xp[u + 256], x2 = xp[u + 512], x3 = xp[u + 768];

    const uint4* hb4 = (const uint4*)(hbuf + cur * 256);
    float a0 = 0.f, a1 = 0.f, a2 = 0.f, a3 = 0.f;
#pragma unroll
    for (int r = 0; r < 8; ++r) {
      const int j4 = (r + t) & 7;       // rotation: loop-variant addresses
      uint4 hv = hb4[q8 + j4];
      uint4 v0 = wr0[j4];
      uint4 v1 = wr1[j4];
      uint4 v2 = wr2[j4];
      uint4 v3 = wr3[j4];
      a0 = dot2(v0.x, hv.x, a0); a0 = dot2(v0.y, hv.y, a0);
      a0 = dot2(v0.z, hv.z, a0); a0 = dot2(v0.w, hv.w, a0);
      a1 = dot2(v1.x, hv.x, a1); a1 = dot2(v1.y, hv.y, a1);
      a1 = dot2(v1.z, hv.z, a1); a1 = dot2(v1.w, hv.w, a1);
      a2 = dot2(v2.x, hv.x, a2); a2 = dot2(v2.y, hv.y, a2);
      a2 = dot2(v2.z, hv.z, a2); a2 = dot2(v2.w, hv.w, a2);
      a3 = dot2(v3.x, hv.x, a3); a3 = dot2(v3.y, hv.y, a3);
      a3 = dot2(v3.z, hv.z, a3); a3 = dot2(v3.w, hv.w, a3);
    }
    // combine K-quarters across the quad
    a0 += __shfl_xor(a0, 1); a0 += __shfl_xor(a0, 2);
    a1 += __shfl_xor(a1, 1); a1 += __shfl_xor(a1, 2);
    a2 += __shfl_xor(a2, 1); a2 += __shfl_xor(a2, 2);
    a3 += __shfl_xor(a3, 1); a3 += __shfl_xor(a3, 2);
    float gi = a0 + x0, gf = a1 + x1, gg = a2 + x2, go = a3 + x3;
    c = sigm(gf) * c + sigm(gi) * fast_tanh(gg);
    float hv_ = sigm(go) * fast_tanh(c);
    if (q == 0) {
      hout[(size_t)(bm + t) * H_ + u] = hv_;
      hbuf[(cur ^ 1) * 256 + u] = f16bits(hv_);
    }
    __syncthreads();
  }

  // ================= fused attention pooling + logits =================
  const int f32 = *(const int*)(ws + OFF_FLAG);
  if (tid < 256) aw[tid] = ldv(attn_w, tid, f32);
  __syncthreads();
  if (tid < 128) {
    const float* hp = hout + (size_t)(bm + tid) * H_;
    float acc = 0.f;
    for (int k = 0; k < 256; k += 4) {
      float4 h4 = *(const float4*)(hp + k);
      acc += h4.x * aw[k] + h4.y * aw[k + 1] + h4.z * aw[k + 2] + h4.w * aw[k + 3];
    }
    sc[tid] = acc + ldv(attn_b, 0, f32);
  }
  __syncthreads();
  if (tid == 0) {
    int len = lengths[b];
    float mx = -3.4e38f;
    for (int s = 0; s < len; ++s) mx = fmaxf(mx, sc[s]);
    float sum = 0.f;
    for (int s = 0; s < 128; ++s) {
      float v = (s < len) ? __expf(sc[s] - mx) : 0.f;
      sc[s] = v; sum += v;
    }
    float inv = 1.f / sum;
    for (int s = 0; s < 128; ++s) sc[s] *= inv;
  }
  __syncthreads();
  if (tid < 256) {
    float acc = 0.f;
    for (int s = 0; s < 128; ++s)
      acc += sc[s] * hout[(size_t)(bm + s) * H_ + tid];
    at[tid] = acc;
  }
  __syncthreads();
  for (int cc = 0; cc < 3; ++cc) {
    if (tid < 256) red[tid] = at[tid] * ldv(out_w, cc * 256 + tid, f32);
    __syncthreads();
    for (int off = 128; off > 0; off >>= 1) {
      if (tid < off) red[tid] += red[tid + off];
      __syncthreads();
    }
    if (tid == 0) {
      float v = red[0] + ldv(out_b, cc, f32);
      if (f32) ((float*)out)[b * 3 + cc] = v;
      else     ((ushort_t*)out)[b * 3 + cc] = f2b(v);
    }
    __syncthreads();
  }
}

// =====================================================================
extern "C" void kernel_launch(void* const* d_in, const int* in_sizes, int n_in,
                              void* d_out, int out_size, void* d_ws, size_t ws_size,
                              hipStream_t stream)
{
  const int* inputs  = (const int*)d_in[0];
  const int* triples = (const int*)d_in[2];
  const int* lengths = (const int*)d_in[3];
  const int* id2     = (const int*)d_in[4];
  const void* emb    = d_in[5];
  const void* ent    = d_in[6];
  const void* rel    = d_in[7];
  const void* W_ent  = d_in[8];
  const void* W_ih   = d_in[9];
  const void* W_hh   = d_in[10];
  const void* b_lstm = d_in[11];
  const void* attn_w = d_in[12];
  const void* attn_b = d_in[13];
  const void* out_w  = d_in[14];
  const void* out_b  = d_in[15];
  char* ws = (char*)d_ws;

  k_detect<<<dim3(1), dim3(64), 0, stream>>>((const uint_t*)emb, ws);
  k0_prep<<<dim3(2639), dim3(256), 0, stream>>>(W_ent, W_ih, W_hh, ws);
  k1_graph<<<dim3(M_ / 8), dim3(256), 0, stream>>>(inputs, triples, id2, emb, ent, rel, ws);
  k2_xg<<<dim3(64, 8), dim3(256), 0, stream>>>(b_lstm, ws);
  k3_lstm<<<dim3(B_), dim3(1024), 0, stream>>>(lengths, attn_w, attn_b,
                                               out_w, out_b, ws, d_out);
}